// Round 5
// baseline (327.102 us; speedup 1.0000x reference)
//
#include <hip/hip_runtime.h>

// Conv 7x7, stride 1, pad 3, on channel 2 only (reference bug: last channel
// broadcast to all 3 output channels). B=16, C=3, H=W=1024, f32 in/out.

#define IMG_H 1024
#define IMG_W 1024
#define KS 7
#define PAD 3
#define TILE 64          // output tile edge (64x64 per block)
#define HALO 70          // TILE + KS - 1
#define LDS_STRIDE 76    // padded row stride (multiple of 4 -> 16B aligned rows)

__global__ __launch_bounds__(256)
void conv7_bcast_kernel(const float* __restrict__ img,
                        const float* __restrict__ ker,
                        float* __restrict__ out) {
    __shared__ __align__(16) float tile[HALO * LDS_STRIDE];

    const int tid = threadIdx.x;
    const int bx  = blockIdx.x;   // tile col 0..15
    const int by  = blockIdx.y;   // tile row 0..15
    const int b   = blockIdx.z;   // batch 0..15

    const int tx0 = bx * TILE;
    const int ty0 = by * TILE;

    // channel 2 of batch b
    const float* __restrict__ src =
        img + ((size_t)b * 3 + 2) * (size_t)(IMG_H * IMG_W);

    // 7x7 kernel -> wave-uniform loads (compiler scalarizes)
    float kf[KS * KS];
    #pragma unroll
    for (int i = 0; i < KS * KS; ++i) kf[i] = ker[i];

    // ---- stage 70x70 halo tile into LDS (zero-pad at image border) ----
    {
        const bool interior = (tx0 >= PAD) && (ty0 >= PAD) &&
                              (tx0 + TILE + PAD <= IMG_W) &&
                              (ty0 + TILE + PAD <= IMG_H);
        if (interior) {
            for (int idx = tid; idx < HALO * HALO; idx += 256) {
                int row = idx / HALO;            // magic-mul, ~3 VALU ops
                int col = idx - row * HALO;
                tile[row * LDS_STRIDE + col] =
                    src[(size_t)(ty0 - PAD + row) * IMG_W + (tx0 - PAD + col)];
            }
        } else {
            for (int idx = tid; idx < HALO * HALO; idx += 256) {
                int row = idx / HALO;
                int col = idx - row * HALO;
                int gy = ty0 - PAD + row;
                int gx = tx0 - PAD + col;
                float v = 0.0f;
                if ((unsigned)gy < IMG_H && (unsigned)gx < IMG_W)
                    v = src[(size_t)gy * IMG_W + gx];
                tile[row * LDS_STRIDE + col] = v;
            }
        }
    }
    __syncthreads();

    // ---- each thread computes a 4x4 output patch ----
    const int lx = (tid & 15) * 4;   // 0..60
    const int ly = (tid >> 4) * 4;   // 0..60

    float acc[4][4];
    #pragma unroll
    for (int r = 0; r < 4; ++r)
        #pragma unroll
        for (int c = 0; c < 4; ++c) acc[r][c] = 0.0f;

    #pragma unroll
    for (int i = 0; i < 10; ++i) {   // 10 input rows cover 4 output rows + 6 halo
        const float* rowp = &tile[(ly + i) * LDS_STRIDE + lx];
        float4 v0 = *(const float4*)(rowp);
        float4 v1 = *(const float4*)(rowp + 4);
        float4 v2 = *(const float4*)(rowp + 8);
        float rv[12] = {v0.x, v0.y, v0.z, v0.w,
                        v1.x, v1.y, v1.z, v1.w,
                        v2.x, v2.y, v2.z, v2.w};
        #pragma unroll
        for (int r = 0; r < 4; ++r) {
            const int ky = i - r;
            if (ky >= 0 && ky < KS) {
                #pragma unroll
                for (int kx = 0; kx < KS; ++kx) {
                    const float kv = kf[ky * KS + kx];
                    #pragma unroll
                    for (int c = 0; c < 4; ++c)
                        acc[r][c] += kv * rv[c + kx];
                }
            }
        }
    }

    // ---- write 4 rows x float4, broadcast to 3 channels ----
    const size_t plane = (size_t)IMG_H * IMG_W;
    const size_t outb  = (size_t)b * 3 * plane;
    #pragma unroll
    for (int r = 0; r < 4; ++r) {
        const int gy = ty0 + ly + r;
        const int gx = tx0 + lx;
        float4 v = make_float4(acc[r][0], acc[r][1], acc[r][2], acc[r][3]);
        size_t base = outb + (size_t)gy * IMG_W + gx;
        *(float4*)(out + base)             = v;
        *(float4*)(out + base + plane)     = v;
        *(float4*)(out + base + 2 * plane) = v;
    }
}

extern "C" void kernel_launch(void* const* d_in, const int* in_sizes, int n_in,
                              void* d_out, int out_size, void* d_ws, size_t ws_size,
                              hipStream_t stream) {
    const float* img = (const float*)d_in[0];  // (16,3,1024,1024) f32
    const float* ker = (const float*)d_in[1];  // (7,7) f32
    float* out = (float*)d_out;                // (16,3,1024,1024) f32

    dim3 grid(IMG_W / TILE, IMG_H / TILE, 16); // 16 x 16 x 16 = 4096 blocks
    conv7_bcast_kernel<<<grid, dim3(256), 0, stream>>>(img, ker, out);
}

// Round 6
// 312.129 us; speedup vs baseline: 1.0480x; 1.0480x over previous
//
#include <hip/hip_runtime.h>

// Conv 7x7, stride 1, pad 3, on channel 2 only (reference bug: last channel
// broadcast to all 3 output channels). B=16, C=3, H=W=1024, f32 in/out.
// Staging via float4 (16B/lane): halo window shifted to gx0 = tx0-4 so both
// global and LDS chunk addresses are 16B-aligned. LDS row = 72 floats.

#define IMG 1024
#define KS 7
#define PAD 3
#define TILE 64
#define HROWS 70         // TILE + KS - 1
#define HCHUNKS 18       // float4 chunks per halo row (72 floats, gx0 = tx0-4)
#define LDS_STRIDE 72    // floats per LDS row (288 B = 18*16B, b128-aligned)

__global__ __launch_bounds__(256)
void conv7_bcast_kernel(const float* __restrict__ img,
                        const float* __restrict__ ker,
                        float* __restrict__ out) {
    __shared__ __align__(16) float tile[HROWS * LDS_STRIDE];  // 20160 B -> 8 blocks/CU

    const int tid = threadIdx.x;
    const int tx0 = blockIdx.x * TILE;
    const int ty0 = blockIdx.y * TILE;
    const int b   = blockIdx.z;

    // channel 2 of batch b
    const float* __restrict__ src =
        img + ((size_t)b * 3 + 2) * (size_t)(IMG * IMG);

    // 7x7 kernel -> wave-uniform loads (compiler scalarizes to s_load)
    float kf[KS * KS];
    #pragma unroll
    for (int i = 0; i < KS * KS; ++i) kf[i] = ker[i];

    // ---- stage halo (70 rows x 72 floats, origin (ty0-3, tx0-4)) ----
    {
        const bool interior = (ty0 >= PAD) && (ty0 + TILE + PAD <= IMG) &&
                              (tx0 >= 4)   && (tx0 + TILE + 4   <= IMG);
        if (interior) {
            for (int idx = tid; idx < HROWS * HCHUNKS; idx += 256) {
                int row = idx / HCHUNKS;          // magic-mul
                int ch  = idx - row * HCHUNKS;
                const float* gp = src + (size_t)(ty0 - PAD + row) * IMG
                                      + (tx0 - 4) + ch * 4;
                *(float4*)&tile[row * LDS_STRIDE + ch * 4] = *(const float4*)gp;
            }
        } else {
            for (int idx = tid; idx < HROWS * HCHUNKS; idx += 256) {
                int row = idx / HCHUNKS;
                int ch  = idx - row * HCHUNKS;
                int gy = ty0 - PAD + row;
                int gx = tx0 - 4 + ch * 4;        // gx % 4 == 0 -> chunk all-in or all-out
                float4 v = make_float4(0.f, 0.f, 0.f, 0.f);
                if ((unsigned)gy < IMG && (unsigned)gx < IMG)
                    v = *(const float4*)(src + (size_t)gy * IMG + gx);
                *(float4*)&tile[row * LDS_STRIDE + ch * 4] = v;
            }
        }
    }
    __syncthreads();

    // ---- each thread computes a 4x4 output patch ----
    const int lx = (tid & 15) * 4;   // 0..60
    const int ly = (tid >> 4) * 4;   // 0..60

    float acc[4][4];
    #pragma unroll
    for (int r = 0; r < 4; ++r)
        #pragma unroll
        for (int c = 0; c < 4; ++c) acc[r][c] = 0.0f;

    #pragma unroll
    for (int i = 0; i < 10; ++i) {   // 10 input rows cover 4 output rows + 6 halo
        const float* rowp = &tile[(ly + i) * LDS_STRIDE + lx];
        float4 v0 = *(const float4*)(rowp);        // cols lx .. lx+3
        float4 v1 = *(const float4*)(rowp + 4);    // cols lx+4 .. lx+7
        float4 v2 = *(const float4*)(rowp + 8);    // cols lx+8 .. lx+11
        float rv[12] = {v0.x, v0.y, v0.z, v0.w,
                        v1.x, v1.y, v1.z, v1.w,
                        v2.x, v2.y, v2.z, v2.w};
        #pragma unroll
        for (int r = 0; r < 4; ++r) {
            const int ky = i - r;
            if (ky >= 0 && ky < KS) {
                #pragma unroll
                for (int kx = 0; kx < KS; ++kx) {
                    const float kv = kf[ky * KS + kx];
                    #pragma unroll
                    for (int c = 0; c < 4; ++c)
                        acc[r][c] += kv * rv[c + kx + 1];   // +1: window shift
                }
            }
        }
    }

    // ---- write 4 rows x float4, broadcast to 3 channels ----
    const size_t plane = (size_t)IMG * IMG;
    const size_t outb  = (size_t)b * 3 * plane;
    #pragma unroll
    for (int r = 0; r < 4; ++r) {
        const int gy = ty0 + ly + r;
        const int gx = tx0 + lx;
        float4 v = make_float4(acc[r][0], acc[r][1], acc[r][2], acc[r][3]);
        size_t base = outb + (size_t)gy * IMG + gx;
        *(float4*)(out + base)             = v;
        *(float4*)(out + base + plane)     = v;
        *(float4*)(out + base + 2 * plane) = v;
    }
}

extern "C" void kernel_launch(void* const* d_in, const int* in_sizes, int n_in,
                              void* d_out, int out_size, void* d_ws, size_t ws_size,
                              hipStream_t stream) {
    const float* img = (const float*)d_in[0];  // (16,3,1024,1024) f32
    const float* ker = (const float*)d_in[1];  // (7,7) f32
    float* out = (float*)d_out;                // (16,3,1024,1024) f32

    dim3 grid(IMG / TILE, IMG / TILE, 16);     // 16 x 16 x 16 = 4096 blocks
    conv7_bcast_kernel<<<grid, dim3(256), 0, stream>>>(img, ker, out);
}